// Round 5
// baseline (825.418 us; speedup 1.0000x reference)
//
#include <hip/hip_runtime.h>
#include <math.h>

#define NN 33
#define KK 32
#define D  64
#define ED 16
#define EPSV 1e-5f

// W column W[:,lane] held in 16 NAMED float4 registers (spill-proof form that
// got R2->R3's 30x traffic fix; keep it).
#define FOR16(M) M(0) M(1) M(2) M(3) M(4) M(5) M(6) M(7) \
                 M(8) M(9) M(10) M(11) M(12) M(13) M(14) M(15)

#define W_DECL(q) float4 Wc##q;
#define W_LOAD(q) Wc##q = make_float4(W_w[(4*(q)+0)*D + lane], \
                                      W_w[(4*(q)+1)*D + lane], \
                                      W_w[(4*(q)+2)*D + lane], \
                                      W_w[(4*(q)+3)*D + lane]);
#define W_FMA(q) { const float4 xv = xrow[(q)];          \
                   acc = fmaf(xv.x, Wc##q.x, acc);       \
                   acc = fmaf(xv.y, Wc##q.y, acc);       \
                   acc = fmaf(xv.z, Wc##q.z, acc);       \
                   acc = fmaf(xv.w, Wc##q.w, acc); }

// ---- kernel 1: edot[b][k] = edges[b][k][:] . (We_w @ aw2) + (We_b.aw2 + attn_b)
// 4 threads per dot, perfectly coalesced float4 reads of edges.
__global__ __launch_bounds__(256)
void edot_kernel(const float* __restrict__ edges,
                 const float* __restrict__ We_w,
                 const float* __restrict__ We_b,
                 const float* __restrict__ attn_w,
                 const float* __restrict__ attn_b,
                 float* __restrict__ edot, int nk)
{
    __shared__ float s_v2[ED];
    __shared__ float s_c;
    const int tid = threadIdx.x;
    if (tid < ED) {
        float v = 0.f;
        #pragma unroll
        for (int o = 0; o < D; ++o) v = fmaf(We_w[tid * D + o], attn_w[2 * D + o], v);
        s_v2[tid] = v;
    } else if (tid == ED) {
        float c = attn_b[0];
        #pragma unroll
        for (int o = 0; o < D; ++o) c = fmaf(We_b[o], attn_w[2 * D + o], c);
        s_c = c;
    }
    __syncthreads();
    const int gid = blockIdx.x * 256 + tid;
    const int k = gid >> 2, e = gid & 3;
    if (k < nk) {
        const float4 ev = ((const float4*)edges)[(size_t)k * 4 + e];
        float p = ev.x * s_v2[4*e+0] + ev.y * s_v2[4*e+1]
                + ev.z * s_v2[4*e+2] + ev.w * s_v2[4*e+3];
        p += __shfl_xor(p, 1, 64);
        p += __shfl_xor(p, 2, 64);
        if (e == 0) edot[k] = p + s_c;
    }
}

// ---- kernel 2: one WAVE per graph b. lane = out-dim. No barriers, no LDS.
// All reductions are intra-wave shuffles; softmax lives on lanes 0..31
// (upper half computes harmless garbage, never read).
__global__
__attribute__((amdgpu_flat_work_group_size(256, 256), amdgpu_waves_per_eu(1, 3)))
void gat_main(const float* __restrict__ nodes,
              const float* __restrict__ W_w,
              const float* __restrict__ W_b,
              const float* __restrict__ attn_w,
              const float* __restrict__ gamma,
              const float* __restrict__ beta,
              const float* __restrict__ edot,
              float* __restrict__ out, int B)
{
    const int tid  = threadIdx.x;
    const int wave = tid >> 6;
    const int lane = tid & 63;

    FOR16(W_DECL)
    FOR16(W_LOAD)

    const float r_wb    = W_b[lane];
    const float r_gamma = gamma[lane];
    const float r_beta  = beta[lane];
    const float aw0     = attn_w[lane];
    const float aw1     = attn_w[D + lane];

    const int stride = gridDim.x * 4;
    for (int b = blockIdx.x * 4 + wave; b < B; b += stride) {
        const float4* __restrict__ xr = (const float4*)(nodes + (size_t)b * (NN * D));

        // h[n] for all 33 rows + fused score reduction.
        float h[NN];
        float sc = 0.f, tdot = 0.f;   // sc: lane k holds score of neighbor k
        #pragma unroll
        for (int n = 0; n < NN; ++n) {
            const float4* xrow = xr + n * 16;    // imm-offset addressing
            float acc = r_wb;
            FOR16(W_FMA)
            h[n] = acc;
            float p = acc * (n == 0 ? aw0 : aw1);
            #pragma unroll
            for (int s = 1; s < 64; s <<= 1) p += __shfl_xor(p, s, 64);
            if (n == 0) tdot = p;
            else        sc = (lane == n - 1) ? p : sc;
        }

        // softmax over 32 neighbors, lane k = neighbor k (halves stay separate
        // under xor-masks < 32; upper half unused).
        const float ed = edot[(size_t)b * KK + (lane & 31)];
        const float sk = sc + tdot + ed;
        float m = sk;
        #pragma unroll
        for (int s = 1; s < 32; s <<= 1) m = fmaxf(m, __shfl_xor(m, s, 64));
        const float ex = __expf(sk - m);
        float sum = ex;
        #pragma unroll
        for (int s = 1; s < 32; s <<= 1) sum += __shfl_xor(sum, s, 64);
        const float attn = ex / sum;

        // messages: broadcast attn_k via readlane, accumulate into target row.
        float msg = 0.f;
        #pragma unroll
        for (int k = 0; k < KK; ++k)
            msg = fmaf(__shfl(attn, k, 64), h[k + 1], msg);
        h[0] += msg;

        // fused LayerNorm + store.
        float* __restrict__ orow = out + (size_t)b * (NN * D) + lane;
        #pragma unroll
        for (int n = 0; n < NN; ++n) {
            const float x = h[n];
            float s1 = x, s2 = x * x;
            #pragma unroll
            for (int s = 1; s < 64; s <<= 1) {
                s1 += __shfl_xor(s1, s, 64);
                s2 += __shfl_xor(s2, s, 64);
            }
            const float mu  = s1 * (1.f / 64.f);
            const float var = s2 * (1.f / 64.f) - mu * mu;
            const float r   = rsqrtf(var + EPSV);
            orow[n * D] = (x - mu) * r * r_gamma + r_beta;
        }
    }
}

extern "C" void kernel_launch(void* const* d_in, const int* in_sizes, int n_in,
                              void* d_out, int out_size, void* d_ws, size_t ws_size,
                              hipStream_t stream)
{
    const float* nodes  = (const float*)d_in[0];
    const float* edges  = (const float*)d_in[1];
    const float* W_w    = (const float*)d_in[2];
    const float* W_b    = (const float*)d_in[3];
    const float* We_w   = (const float*)d_in[4];
    const float* We_b   = (const float*)d_in[5];
    const float* attn_w = (const float*)d_in[6];
    const float* attn_b = (const float*)d_in[7];
    const float* gamma  = (const float*)d_in[8];
    const float* beta   = (const float*)d_in[9];
    float* out  = (float*)d_out;
    float* edot = (float*)d_ws;               // B*32 floats = 2 MB scratch

    const int B  = in_sizes[0] / (NN * D);
    const int nk = B * KK;

    edot_kernel<<<(nk * 4 + 255) / 256, 256, 0, stream>>>(
        edges, We_w, We_b, attn_w, attn_b, edot, nk);

    gat_main<<<1024, 256, 0, stream>>>(
        nodes, W_w, W_b, attn_w, gamma, beta, edot, out, B);
}